// Round 4
// baseline (99.568 us; speedup 1.0000x reference)
//
#include <hip/hip_runtime.h>
#include <cstddef>

#define FCNT 2048
#define SEG 256
#define LSTEP 4
#define HALF 1024

#define GRAV 9.81007f
#define GYRO_COV (0.00016968f * 0.00016968f)
#define ACC_COV (0.002f * 0.002f)

// Series coefficients for SO3 Exp / right Jacobian: A=sin t/t, Bc=(1-cos t)/t^2,
// Cc=(t-sin t)/t^3.  For this data t^2 <= ~6e-4 so the series is fp32-exact;
// trig fallback kept for robustness (uniformly untaken branch).
__device__ __forceinline__ void exp_coefs(float t2, float& A, float& Bc, float& Cc) {
  A  = 1.f     + t2 * (-1.f/6.f   + t2 * (1.f/120.f  + t2 * (-1.f/5040.f)));
  Bc = 0.5f    + t2 * (-1.f/24.f  + t2 * (1.f/720.f  + t2 * (-1.f/40320.f)));
  Cc = 1.f/6.f + t2 * (-1.f/120.f + t2 * (1.f/5040.f + t2 * (-1.f/362880.f)));
  if (t2 > 0.004f) {
    float t = sqrtf(t2);
    float sn = __sinf(t), cs = __cosf(t);
    A  = sn / t;
    Bc = (1.f - cs) / t2;
    Cc = (t - sn) / (t2 * t);
  }
}

// dR = I + A*S(w) + Bc*(w w^T - t2 I), row-major
__device__ __forceinline__ void make_dR(float w0, float w1, float w2, float t2,
                                        float A, float Bc, float* dR) {
  float w01 = w0*w1, w02 = w0*w2, w12 = w1*w2;
  dR[0] = 1.f + Bc*(w0*w0 - t2); dR[1] = Bc*w01 - A*w2;         dR[2] = Bc*w02 + A*w1;
  dR[3] = Bc*w01 + A*w2;         dR[4] = 1.f + Bc*(w1*w1 - t2); dR[5] = Bc*w12 - A*w0;
  dR[6] = Bc*w02 - A*w1;         dR[7] = Bc*w12 + A*w0;         dR[8] = 1.f + Bc*(w2*w2 - t2);
}

__device__ __forceinline__ void mm3(const float* a, const float* b, float* c) {
#pragma unroll
  for (int i = 0; i < 3; ++i) {
    float a0 = a[i*3+0], a1 = a[i*3+1], a2 = a[i*3+2];
    c[i*3+0] = a0*b[0] + a1*b[3] + a2*b[6];
    c[i*3+1] = a0*b[1] + a1*b[4] + a2*b[7];
    c[i*3+2] = a0*b[2] + a1*b[5] + a2*b[8];
  }
}

// o = pa (earlier) then st (later); o may alias either input.
// layout: [0..8]=R row-major, [9..11]=v, [12..14]=p, [15]=t
__device__ __forceinline__ void compose16(const float* pa, const float* stv, float* o) {
  float nR[9];
  mm3(pa, stv, nR);
  float nv0 = pa[9]  + pa[0]*stv[9] + pa[1]*stv[10] + pa[2]*stv[11];
  float nv1 = pa[10] + pa[3]*stv[9] + pa[4]*stv[10] + pa[5]*stv[11];
  float nv2 = pa[11] + pa[6]*stv[9] + pa[7]*stv[10] + pa[8]*stv[11];
  float qt = stv[15];
  float np0 = pa[12] + pa[9]*qt  + pa[0]*stv[12] + pa[1]*stv[13] + pa[2]*stv[14];
  float np1 = pa[13] + pa[10]*qt + pa[3]*stv[12] + pa[4]*stv[13] + pa[5]*stv[14];
  float np2 = pa[14] + pa[11]*qt + pa[6]*stv[12] + pa[7]*stv[13] + pa[8]*stv[14];
  float nt = pa[15] + qt;
#pragma unroll
  for (int i = 0; i < 9; ++i) o[i] = nR[i];
  o[9]=nv0; o[10]=nv1; o[11]=nv2;
  o[12]=np0; o[13]=np1; o[14]=np2;
  o[15]=nt;
}

// 4-step local integration from identity; vectorized input loads.
__device__ __forceinline__ void phaseA(const float* __restrict__ dtp,
                                       const float* __restrict__ gyp,
                                       const float* __restrict__ acp,
                                       size_t base, float* st) {
  float dl[LSTEP], gl[LSTEP*3], al[LSTEP*3];
  const float4 x0 = *reinterpret_cast<const float4*>(dtp + base);     // 16B aligned
  dl[0]=x0.x; dl[1]=x0.y; dl[2]=x0.z; dl[3]=x0.w;
  const float4* qg = reinterpret_cast<const float4*>(gyp + base*3);   // 48B aligned
  const float4* qa = reinterpret_cast<const float4*>(acp + base*3);
#pragma unroll
  for (int i = 0; i < 3; ++i) {
    float4 xg = qg[i];
    gl[i*4+0]=xg.x; gl[i*4+1]=xg.y; gl[i*4+2]=xg.z; gl[i*4+3]=xg.w;
    float4 xa = qa[i];
    al[i*4+0]=xa.x; al[i*4+1]=xa.y; al[i*4+2]=xa.z; al[i*4+3]=xa.w;
  }
  st[0]=1;st[1]=0;st[2]=0; st[3]=0;st[4]=1;st[5]=0; st[6]=0;st[7]=0;st[8]=1;
#pragma unroll
  for (int i = 9; i < 16; ++i) st[i] = 0.f;
#pragma unroll
  for (int j = 0; j < LSTEP; ++j) {
    float dd = dl[j];
    float w0 = gl[j*3+0]*dd, w1 = gl[j*3+1]*dd, w2 = gl[j*3+2]*dd;
    float t2 = w0*w0 + w1*w1 + w2*w2;
    float A, Bc, Cc;
    exp_coefs(t2, A, Bc, Cc);
    (void)Cc;
    float dR[9];
    make_dR(w0, w1, w2, t2, A, Bc, dR);
    float a0 = al[j*3+0], a1 = al[j*3+1], a2 = al[j*3+2];
    float Ra0 = st[0]*a0 + st[1]*a1 + st[2]*a2;
    float Ra1 = st[3]*a0 + st[4]*a1 + st[5]*a2;
    float Ra2 = st[6]*a0 + st[7]*a1 + st[8]*a2;
    float hh = 0.5f*dd*dd;
    st[12] += st[9]*dd  + hh*Ra0;
    st[13] += st[10]*dd + hh*Ra1;
    st[14] += st[11]*dd + hh*Ra2;
    st[9] += Ra0*dd; st[10] += Ra1*dd; st[11] += Ra2*dd;
    float Rn[9];
    mm3(st, dR, Rn);
#pragma unroll
    for (int i = 0; i < 9; ++i) st[i] = Rn[i];
    st[15] += dd;
  }
}

// Hillis-Steele inclusive scan over SEG threads; buf component-major (conflict-free).
__device__ __forceinline__ void blockscan(float (*buf)[SEG], float* st, int s) {
#pragma unroll
  for (int i = 0; i < 16; ++i) buf[i][s] = st[i];
  __syncthreads();
#pragma unroll
  for (int off = 1; off < SEG; off <<= 1) {
    float pa[16];
    const bool act = (s >= off);
    if (act) {
#pragma unroll
      for (int i = 0; i < 16; ++i) pa[i] = buf[i][s - off];
    }
    __syncthreads();
    if (act) {
      compose16(pa, st, st);
#pragma unroll
      for (int i = 0; i < 16; ++i) buf[i][s] = st[i];
    }
    __syncthreads();
  }
}

// ---------------- K1: per-half-batch totals ----------------
__global__ __launch_bounds__(SEG, 4)
void k1_totals(const float* __restrict__ dtp, const float* __restrict__ gyp,
               const float* __restrict__ acp, float* __restrict__ ws_tot)
{
  __shared__ float buf[16][SEG];
  const int s = threadIdx.x;
  const int bid = blockIdx.x;
  const size_t base = (size_t)bid * HALF + (size_t)s * LSTEP;
  float st[16];
  phaseA(dtp, gyp, acp, base, st);
  blockscan(buf, st, s);
  if (s < 16) ws_tot[(size_t)bid*16 + s] = buf[s][SEG-1];
}

// ---------------- K2: main (scan + cov partials + outputs) ----------------
__global__ __launch_bounds__(SEG, 4)
void k2_main(const float* __restrict__ dtp, const float* __restrict__ gyp,
             const float* __restrict__ acp, const float* __restrict__ ip0,
             const float* __restrict__ iR0, const float* __restrict__ iv0,
             float* __restrict__ out, const float* __restrict__ ws_tot,
             float* __restrict__ ws_part, int B)
{
  // smem aliased: scan buf (16x256 = 4096 floats) first, rot stage (9216 floats) later
  __shared__ float smem[9 * HALF];
  __shared__ float rbuf[4][48];
  float (*buf)[SEG] = reinterpret_cast<float(*)[SEG]>(smem);

  const int s = threadIdx.x;
  const int bid = blockIdx.x;
  const int b = bid >> 1, h = bid & 1;
  const size_t base = (size_t)bid * HALF + (size_t)s * LSTEP;  // global frame index
  const size_t NBF = (size_t)B * FCNT;
  float* orot = out;
  float* ovel = out + NBF * 9;
  float* opos = out + NBF * 12;

  float st[16];
  phaseA(dtp, gyp, acp, base, st);
  blockscan(buf, st, s);

  // full-chain totals (raw frame) from ws
  float Tv0, Tv1, Tv2, Tp0, Tp1, Tp2, Tt;
  {
    float t0[16], t1[16], TF[16];
    const float* q0 = ws_tot + (size_t)(b*2) * 16;
#pragma unroll
    for (int i = 0; i < 16; ++i) { t0[i] = q0[i]; t1[i] = q0[16+i]; }
    compose16(t0, t1, TF);
    Tv0=TF[9]; Tv1=TF[10]; Tv2=TF[11]; Tp0=TF[12]; Tp1=TF[13]; Tp2=TF[14]; Tt=TF[15];
  }

  // exclusive carry in full-chain raw frame
  float cr[16];
  if (s == 0) {
    cr[0]=1;cr[1]=0;cr[2]=0; cr[3]=0;cr[4]=1;cr[5]=0; cr[6]=0;cr[7]=0;cr[8]=1;
#pragma unroll
    for (int i = 9; i < 16; ++i) cr[i] = 0.f;
  } else {
#pragma unroll
    for (int i = 0; i < 16; ++i) cr[i] = buf[i][s-1];
  }
  if (h) {
    float g0[16];
    const float* q0 = ws_tot + (size_t)(b*2) * 16;
#pragma unroll
    for (int i = 0; i < 16; ++i) g0[i] = q0[i];
    compose16(g0, cr, cr);
  }

  // ---------------- C2: covariance accumulation (raw full frame) ----------------
  float cR[9], cv[3], cp[3], ct;
#pragma unroll
  for (int i = 0; i < 9; ++i) cR[i] = cr[i];
  cv[0]=cr[9]; cv[1]=cr[10]; cv[2]=cr[11];
  cp[0]=cr[12]; cp[1]=cr[13]; cp[2]=cr[14];
  ct = cr[15];

  float aS0=0,aS1=0,aS2=0,aS3=0,aS4=0,aS5=0;
  float aU0=0,aU1=0,aU2=0,aU3=0,aU4=0,aU5=0,aU6=0,aU7=0,aU8=0;
  float aV0=0,aV1=0,aV2=0,aV3=0,aV4=0,aV5=0,aV6=0,aV7=0,aV8=0;
  float b220=0,b221=0,b222=0,b223=0,b224=0,b225=0;
  float b230=0,b231=0,b232=0,b233=0,b234=0,b235=0,b236=0,b237=0,b238=0;
  float b330=0,b331=0,b332=0,b333=0,b334=0,b335=0;
  float sa=0.f, sb=0.f, sc=0.f;

#pragma unroll
  for (int j = 0; j < LSTEP; ++j) {
    const size_t fo = base + j;
    const float dd = dtp[fo];
    const float g0_ = gyp[fo*3+0], g1_ = gyp[fo*3+1], g2_ = gyp[fo*3+2];
    const float a0 = acp[fo*3+0], a1 = acp[fo*3+1], a2 = acp[fo*3+2];
    const float w0 = g0_*dd, w1 = g1_*dd, w2 = g2_*dd;
    const float t2 = w0*w0 + w1*w1 + w2*w2;
    float A, Bc, Cc;
    exp_coefs(t2, A, Bc, Cc);
    float dR[9];
    make_dR(w0, w1, w2, t2, A, Bc, dR);
    float J[9];
    {
      float w01 = w0*w1, w02 = w0*w2, w12 = w1*w2;
      J[0] = 1.f + Cc*(w0*w0 - t2); J[1] =  Bc*w2 + Cc*w01;        J[2] = -Bc*w1 + Cc*w02;
      J[3] = -Bc*w2 + Cc*w01;       J[4] = 1.f + Cc*(w1*w1 - t2);  J[5] =  Bc*w0 + Cc*w12;
      J[6] =  Bc*w1 + Cc*w02;       J[7] = -Bc*w0 + Cc*w12;        J[8] = 1.f + Cc*(w2*w2 - t2);
    }
    const float Ra0 = cR[0]*a0 + cR[1]*a1 + cR[2]*a2;
    const float Ra1 = cR[3]*a0 + cR[4]*a1 + cR[5]*a2;
    const float Ra2 = cR[6]*a0 + cR[7]*a1 + cR[8]*a2;
    const float hh = 0.5f*dd*dd;
    const float pn0 = cp[0] + cv[0]*dd + hh*Ra0;
    const float pn1 = cp[1] + cv[1]*dd + hh*Ra1;
    const float pn2 = cp[2] + cv[2]*dd + hh*Ra2;
    const float vn0 = cv[0] + Ra0*dd;
    const float vn1 = cv[1] + Ra1*dd;
    const float vn2 = cv[2] + Ra2*dd;
    float Rn[9];
    mm3(cR, dR, Rn);
    const float tn = ct + dd;

    float Q[9];
    mm3(Rn, J, Q);
    const float sg = GYRO_COV*dd*dd;
    const float S00 = sg*(Q[0]*Q[0] + Q[1]*Q[1] + Q[2]*Q[2]);
    const float S01 = sg*(Q[0]*Q[3] + Q[1]*Q[4] + Q[2]*Q[5]);
    const float S02 = sg*(Q[0]*Q[6] + Q[1]*Q[7] + Q[2]*Q[8]);
    const float S11 = sg*(Q[3]*Q[3] + Q[4]*Q[4] + Q[5]*Q[5]);
    const float S12 = sg*(Q[3]*Q[6] + Q[4]*Q[7] + Q[5]*Q[8]);
    const float S22 = sg*(Q[6]*Q[6] + Q[7]*Q[7] + Q[8]*Q[8]);
    const float z = Tt - tn;
    const float wv0 = Tv0 - vn0, wv1 = Tv1 - vn1, wv2 = Tv2 - vn2;
    const float wp0 = Tp0 - pn0 - z*vn0;
    const float wp1 = Tp1 - pn1 - z*vn1;
    const float wp2 = Tp2 - pn2 - z*vn2;
    const float U00=S01*wv2-S02*wv1, U01=S02*wv0-S00*wv2, U02=S00*wv1-S01*wv0;
    const float U10=S11*wv2-S12*wv1, U11=S12*wv0-S01*wv2, U12=S01*wv1-S11*wv0;
    const float U20=S12*wv2-S22*wv1, U21=S22*wv0-S02*wv2, U22=S02*wv1-S12*wv0;
    const float V00=S01*wp2-S02*wp1, V01=S02*wp0-S00*wp2, V02=S00*wp1-S01*wp0;
    const float V10=S11*wp2-S12*wp1, V11=S12*wp0-S01*wp2, V12=S01*wp1-S11*wp0;
    const float V20=S12*wp2-S22*wp1, V21=S22*wp0-S02*wp2, V22=S02*wp1-S12*wp0;
    aS0+=S00; aS1+=S01; aS2+=S02; aS3+=S11; aS4+=S12; aS5+=S22;
    aU0+=U00; aU1+=U01; aU2+=U02; aU3+=U10; aU4+=U11; aU5+=U12; aU6+=U20; aU7+=U21; aU8+=U22;
    aV0+=V00; aV1+=V01; aV2+=V02; aV3+=V10; aV4+=V11; aV5+=V12; aV6+=V20; aV7+=V21; aV8+=V22;
    b220 += wv1*U20 - wv2*U10;
    b221 += wv1*U21 - wv2*U11;
    b222 += wv1*U22 - wv2*U12;
    b223 += wv2*U01 - wv0*U21;
    b224 += wv2*U02 - wv0*U22;
    b225 += wv0*U12 - wv1*U02;
    b230 += wv1*V20 - wv2*V10;
    b231 += wv1*V21 - wv2*V11;
    b232 += wv1*V22 - wv2*V12;
    b233 += wv2*V00 - wv0*V20;
    b234 += wv2*V01 - wv0*V21;
    b235 += wv2*V02 - wv0*V22;
    b236 += wv0*V10 - wv1*V00;
    b237 += wv0*V11 - wv1*V01;
    b238 += wv0*V12 - wv1*V02;
    b330 += wp1*V20 - wp2*V10;
    b331 += wp1*V21 - wp2*V11;
    b332 += wp1*V22 - wp2*V12;
    b333 += wp2*V01 - wp0*V21;
    b334 += wp2*V02 - wp0*V22;
    b335 += wp0*V12 - wp1*V02;
    const float d2 = dd*dd;
    const float aa = ACC_COV*d2;
    const float bbq = 0.5f*ACC_COV*d2*dd;
    sa += aa;
    sb += aa*z + bbq;
    sc += z*(aa*z + 2.f*bbq) + 0.25f*ACC_COV*d2*d2;

#pragma unroll
    for (int i = 0; i < 9; ++i) cR[i] = Rn[i];
    cv[0]=vn0; cv[1]=vn1; cv[2]=vn2;
    cp[0]=pn0; cp[1]=pn1; cp[2]=pn2;
    ct = tn;
  }

  // wave shfl-reduce + cross-wave partial write
  {
    float red[48] = {aS0,aS1,aS2,aS3,aS4,aS5,
                     aU0,aU1,aU2,aU3,aU4,aU5,aU6,aU7,aU8,
                     aV0,aV1,aV2,aV3,aV4,aV5,aV6,aV7,aV8,
                     b220,b221,b222,b223,b224,b225,
                     b230,b231,b232,b233,b234,b235,b236,b237,b238,
                     b330,b331,b332,b333,b334,b335,
                     sa,sb,sc};
#pragma unroll
    for (int i = 0; i < 48; ++i) {
      float x = red[i];
      x += __shfl_down(x, 32);
      x += __shfl_down(x, 16);
      x += __shfl_down(x, 8);
      x += __shfl_down(x, 4);
      x += __shfl_down(x, 2);
      x += __shfl_down(x, 1);
      red[i] = x;
    }
    const int lane = s & 63;
    const int wid  = s >> 6;
    if (lane == 0) {
#pragma unroll
      for (int i = 0; i < 48; ++i) rbuf[wid][i] = red[i];
    }
  }
  __syncthreads();
  if (s < 48)
    ws_part[(size_t)bid*48 + s] = rbuf[0][s] + rbuf[1][s] + rbuf[2][s] + rbuf[3][s];

  // ---------------- C1: outputs in pre-rotated frame ----------------
  // re-read raw exclusive carry from scan buf (still intact)
  float cr2[16];
  if (s == 0) {
    cr2[0]=1;cr2[1]=0;cr2[2]=0; cr2[3]=0;cr2[4]=1;cr2[5]=0; cr2[6]=0;cr2[7]=0;cr2[8]=1;
#pragma unroll
    for (int i = 9; i < 16; ++i) cr2[i] = 0.f;
  } else {
#pragma unroll
    for (int i = 0; i < 16; ++i) cr2[i] = buf[i][s-1];
  }
  if (h) {
    float g0[16];
    const float* q0 = ws_tot + (size_t)(b*2) * 16;
#pragma unroll
    for (int i = 0; i < 16; ++i) g0[i] = q0[i];
    compose16(g0, cr2, cr2);
  }

  float R0g[9];
#pragma unroll
  for (int i = 0; i < 9; ++i) R0g[i] = iR0[i];
  const float p0x = ip0[0], p0y = ip0[1], p0z = ip0[2];
  const float v0x = iv0[0], v0y = iv0[1], v0z = iv0[2];

  float tR[9];
  mm3(R0g, cr2, tR);
  float tv0 = R0g[0]*cr2[9] + R0g[1]*cr2[10] + R0g[2]*cr2[11];
  float tv1 = R0g[3]*cr2[9] + R0g[4]*cr2[10] + R0g[5]*cr2[11];
  float tv2 = R0g[6]*cr2[9] + R0g[7]*cr2[10] + R0g[8]*cr2[11];
  float tp0 = R0g[0]*cr2[12] + R0g[1]*cr2[13] + R0g[2]*cr2[14];
  float tp1 = R0g[3]*cr2[12] + R0g[4]*cr2[13] + R0g[5]*cr2[14];
  float tp2 = R0g[6]*cr2[12] + R0g[7]*cr2[13] + R0g[8]*cr2[14];
  float ctt = cr2[15];

  __syncthreads();   // all scan-buf reads done; smem becomes the rot stage

  float vloc[LSTEP*3], ploc[LSTEP*3];
#pragma unroll
  for (int j = 0; j < LSTEP; ++j) {
    const size_t fo = base + j;
    const float dd = dtp[fo];
    const float g0_ = gyp[fo*3+0], g1_ = gyp[fo*3+1], g2_ = gyp[fo*3+2];
    const float a0 = acp[fo*3+0], a1 = acp[fo*3+1], a2 = acp[fo*3+2];
    const float w0 = g0_*dd, w1 = g1_*dd, w2 = g2_*dd;
    const float t2 = w0*w0 + w1*w1 + w2*w2;
    float A, Bc, Cc;
    exp_coefs(t2, A, Bc, Cc);
    (void)Cc;
    float dR[9];
    make_dR(w0, w1, w2, t2, A, Bc, dR);
    const float Ra0 = tR[0]*a0 + tR[1]*a1 + tR[2]*a2;
    const float Ra1 = tR[3]*a0 + tR[4]*a1 + tR[5]*a2;
    const float Ra2 = tR[6]*a0 + tR[7]*a1 + tR[8]*a2;
    const float hh = 0.5f*dd*dd;
    tp0 += tv0*dd + hh*Ra0;
    tp1 += tv1*dd + hh*Ra1;
    tp2 += tv2*dd + hh*Ra2;
    tv0 += Ra0*dd; tv1 += Ra1*dd; tv2 += Ra2*dd;
    float Rn[9];
    mm3(tR, dR, Rn);
#pragma unroll
    for (int i = 0; i < 9; ++i) {
      tR[i] = Rn[i];
      smem[(s*LSTEP + j)*9 + i] = Rn[i];   // rot stage, frame-major (mirrors global)
    }
    ctt += dd;
    vloc[j*3+0] = v0x + tv0;
    vloc[j*3+1] = v0y + tv1;
    vloc[j*3+2] = v0z + tv2 - GRAV*ctt;
    ploc[j*3+0] = p0x + v0x*ctt + tp0;
    ploc[j*3+1] = p0y + v0y*ctt + tp1;
    ploc[j*3+2] = p0z + v0z*ctt + tp2 - 0.5f*GRAV*ctt*ctt;
  }
  __syncthreads();

  // cooperative rot flush: stride-1 lane-contiguous dwords -> full-line HBM writes
  {
    const size_t rbase = (size_t)bid * (HALF*9);
#pragma unroll
    for (int k = 0; k < HALF*9/SEG; ++k)     // 36 iters
      orot[rbase + (size_t)k*SEG + s] = smem[k*SEG + s];
  }
  // vel/pos bursts (48B per thread, 16B aligned)
  {
    float4* vq = reinterpret_cast<float4*>(ovel + base*3);
#pragma unroll
    for (int k = 0; k < LSTEP*3/4; ++k)
      vq[k] = make_float4(vloc[k*4+0], vloc[k*4+1], vloc[k*4+2], vloc[k*4+3]);
    float4* pq = reinterpret_cast<float4*>(opos + base*3);
#pragma unroll
    for (int k = 0; k < LSTEP*3/4; ++k)
      pq[k] = make_float4(ploc[k*4+0], ploc[k*4+1], ploc[k*4+2], ploc[k*4+3]);
  }
}

// ---------------- K3: covariance assembly ----------------
__global__ void k3_cov(const float* __restrict__ ws_tot, const float* __restrict__ ws_part,
                       float* __restrict__ out, int B)
{
  const int b = blockIdx.x;
  if (threadIdx.x != 0) return;
  float T[48];
  const float* q0 = ws_part + (size_t)(b*2) * 48;
#pragma unroll
  for (int i = 0; i < 48; ++i) T[i] = q0[i] + q0[48+i];
  float t0[16], t1[16], TF[16];
  const float* w0 = ws_tot + (size_t)(b*2) * 16;
#pragma unroll
  for (int i = 0; i < 16; ++i) { t0[i] = w0[i]; t1[i] = w0[16+i]; }
  compose16(t0, t1, TF);
  float TR[9];
#pragma unroll
  for (int i = 0; i < 9; ++i) TR[i] = TF[i];                       // DrF (raw)
  float Rt[9] = {TR[0],TR[3],TR[6], TR[1],TR[4],TR[7], TR[2],TR[5],TR[8]};
  float Sm[9]  = {T[0],T[1],T[2], T[1],T[3],T[4], T[2],T[4],T[5]};
  float Um[9]  = {T[6],T[7],T[8], T[9],T[10],T[11], T[12],T[13],T[14]};
  float Vm[9]  = {T[15],T[16],T[17], T[18],T[19],T[20], T[21],T[22],T[23]};
  float W22[9] = {T[24],T[25],T[26], T[25],T[27],T[28], T[26],T[28],T[29]};
  float W23[9] = {T[30],T[31],T[32], T[33],T[34],T[35], T[36],T[37],T[38]};
  float W33[9] = {T[39],T[40],T[41], T[40],T[42],T[43], T[41],T[43],T[44]};
  const float ssa = T[45], ssb = T[46], ssc = T[47];
  float T1[9], C11[9], C12[9], C13[9];
  mm3(Rt, Sm, T1);
  mm3(T1, TR, C11);
  mm3(Rt, Um, C12);
  mm3(Rt, Vm, C13);
  float* co = out + (size_t)B*FCNT*15 + (size_t)b*81;
#pragma unroll
  for (int i = 0; i < 3; ++i) {
#pragma unroll
    for (int jj = 0; jj < 3; ++jj) {
      co[i*9 + jj]       = C11[i*3+jj];
      co[i*9 + 3 + jj]   = C12[i*3+jj];
      co[i*9 + 6 + jj]   = C13[i*3+jj];
      co[(3+i)*9 + jj]     = C12[jj*3+i];
      co[(3+i)*9 + 3 + jj] = -W22[i*3+jj] + (i==jj ? ssa : 0.f);
      co[(3+i)*9 + 6 + jj] = -W23[i*3+jj] + (i==jj ? ssb : 0.f);
      co[(6+i)*9 + jj]     = C13[jj*3+i];
      co[(6+i)*9 + 3 + jj] = -W23[jj*3+i] + (i==jj ? ssb : 0.f);
      co[(6+i)*9 + 6 + jj] = -W33[i*3+jj] + (i==jj ? ssc : 0.f);
    }
  }
}

extern "C" void kernel_launch(void* const* d_in, const int* in_sizes, int n_in,
                              void* d_out, int out_size, void* d_ws, size_t ws_size,
                              hipStream_t stream) {
  const float* dt   = (const float*)d_in[0];
  const float* gyro = (const float*)d_in[1];
  const float* acc  = (const float*)d_in[2];
  const float* ip   = (const float*)d_in[3];
  const float* iR   = (const float*)d_in[4];
  const float* iv   = (const float*)d_in[5];
  float* out = (float*)d_out;
  const int B  = in_sizes[0] / FCNT;     // dt is (B, F, 1)
  const int NB = 2 * B;                  // half-batch blocks
  float* ws_tot  = (float*)d_ws;                         // NB*16 floats
  float* ws_part = ws_tot + (size_t)NB * 16;             // NB*48 floats  (total 256KB @ B=512)
  k1_totals<<<dim3(NB), dim3(SEG), 0, stream>>>(dt, gyro, acc, ws_tot);
  k2_main<<<dim3(NB), dim3(SEG), 0, stream>>>(dt, gyro, acc, ip, iR, iv, out, ws_tot, ws_part, B);
  k3_cov<<<dim3(B), dim3(64), 0, stream>>>(ws_tot, ws_part, out, B);
}

// Round 5
// 60.554 us; speedup vs baseline: 1.6443x; 1.6443x over previous
//
#include <hip/hip_runtime.h>
#include <cstddef>

#define FCNT 2048
#define SEG 256
#define LSTEP 4
#define HALF 1024

#define GRAV 9.81007f
#define GYRO_COV (0.00016968f * 0.00016968f)
#define ACC_COV (0.002f * 0.002f)

// Series coefficients for SO3 Exp / right Jacobian: A=sin t/t, Bc=(1-cos t)/t^2,
// Cc=(t-sin t)/t^3.  For this data t^2 <= ~6e-4 so the series is fp32-exact;
// trig fallback kept for robustness (uniformly untaken branch).
__device__ __forceinline__ void exp_coefs(float t2, float& A, float& Bc, float& Cc) {
  A  = 1.f     + t2 * (-1.f/6.f   + t2 * (1.f/120.f  + t2 * (-1.f/5040.f)));
  Bc = 0.5f    + t2 * (-1.f/24.f  + t2 * (1.f/720.f  + t2 * (-1.f/40320.f)));
  Cc = 1.f/6.f + t2 * (-1.f/120.f + t2 * (1.f/5040.f + t2 * (-1.f/362880.f)));
  if (t2 > 0.004f) {
    float t = sqrtf(t2);
    float sn = __sinf(t), cs = __cosf(t);
    A  = sn / t;
    Bc = (1.f - cs) / t2;
    Cc = (t - sn) / (t2 * t);
  }
}

// dR = I + A*S(w) + Bc*(w w^T - t2 I), row-major
__device__ __forceinline__ void make_dR(float w0, float w1, float w2, float t2,
                                        float A, float Bc, float* dR) {
  float w01 = w0*w1, w02 = w0*w2, w12 = w1*w2;
  dR[0] = 1.f + Bc*(w0*w0 - t2); dR[1] = Bc*w01 - A*w2;         dR[2] = Bc*w02 + A*w1;
  dR[3] = Bc*w01 + A*w2;         dR[4] = 1.f + Bc*(w1*w1 - t2); dR[5] = Bc*w12 - A*w0;
  dR[6] = Bc*w02 - A*w1;         dR[7] = Bc*w12 + A*w0;         dR[8] = 1.f + Bc*(w2*w2 - t2);
}

__device__ __forceinline__ void mm3(const float* a, const float* b, float* c) {
#pragma unroll
  for (int i = 0; i < 3; ++i) {
    float a0 = a[i*3+0], a1 = a[i*3+1], a2 = a[i*3+2];
    c[i*3+0] = a0*b[0] + a1*b[3] + a2*b[6];
    c[i*3+1] = a0*b[1] + a1*b[4] + a2*b[7];
    c[i*3+2] = a0*b[2] + a1*b[5] + a2*b[8];
  }
}

// M = R^T @ Mp @ R  (un-rotate a matrix accumulated in the pre-rotated frame)
__device__ __forceinline__ void conjT(const float* R, const float* Mp, float* M) {
  float tmp[9];
#pragma unroll
  for (int i = 0; i < 3; ++i)
#pragma unroll
    for (int j = 0; j < 3; ++j)
      tmp[i*3+j] = R[0+i]*Mp[0+j] + R[3+i]*Mp[3+j] + R[6+i]*Mp[6+j];  // R^T @ Mp
  mm3(tmp, R, M);
}

// o = pa (earlier) then st (later); o may alias either input.
// layout: [0..8]=R row-major, [9..11]=v, [12..14]=p, [15]=t
__device__ __forceinline__ void compose16(const float* pa, const float* stv, float* o) {
  float nR[9];
  mm3(pa, stv, nR);
  float nv0 = pa[9]  + pa[0]*stv[9] + pa[1]*stv[10] + pa[2]*stv[11];
  float nv1 = pa[10] + pa[3]*stv[9] + pa[4]*stv[10] + pa[5]*stv[11];
  float nv2 = pa[11] + pa[6]*stv[9] + pa[7]*stv[10] + pa[8]*stv[11];
  float qt = stv[15];
  float np0 = pa[12] + pa[9]*qt  + pa[0]*stv[12] + pa[1]*stv[13] + pa[2]*stv[14];
  float np1 = pa[13] + pa[10]*qt + pa[3]*stv[12] + pa[4]*stv[13] + pa[5]*stv[14];
  float np2 = pa[14] + pa[11]*qt + pa[6]*stv[12] + pa[7]*stv[13] + pa[8]*stv[14];
  float nt = pa[15] + qt;
#pragma unroll
  for (int i = 0; i < 9; ++i) o[i] = nR[i];
  o[9]=nv0; o[10]=nv1; o[11]=nv2;
  o[12]=np0; o[13]=np1; o[14]=np2;
  o[15]=nt;
}

__device__ __forceinline__ void load_seg(const float* __restrict__ dtp,
                                         const float* __restrict__ gyp,
                                         const float* __restrict__ acp,
                                         size_t base, float* dl, float* gl, float* al) {
  const float4 x0 = *reinterpret_cast<const float4*>(dtp + base);     // 16B aligned
  dl[0]=x0.x; dl[1]=x0.y; dl[2]=x0.z; dl[3]=x0.w;
  const float4* qg = reinterpret_cast<const float4*>(gyp + base*3);   // 48B aligned
  const float4* qa = reinterpret_cast<const float4*>(acp + base*3);
#pragma unroll
  for (int i = 0; i < 3; ++i) {
    float4 xg = qg[i];
    gl[i*4+0]=xg.x; gl[i*4+1]=xg.y; gl[i*4+2]=xg.z; gl[i*4+3]=xg.w;
    float4 xa = qa[i];
    al[i*4+0]=xa.x; al[i*4+1]=xa.y; al[i*4+2]=xa.z; al[i*4+3]=xa.w;
  }
}

// 4-step local integration from identity.
__device__ __forceinline__ void integrate_seg(const float* dl, const float* gl,
                                              const float* al, float* st) {
  st[0]=1;st[1]=0;st[2]=0; st[3]=0;st[4]=1;st[5]=0; st[6]=0;st[7]=0;st[8]=1;
#pragma unroll
  for (int i = 9; i < 16; ++i) st[i] = 0.f;
#pragma unroll
  for (int j = 0; j < LSTEP; ++j) {
    float dd = dl[j];
    float w0 = gl[j*3+0]*dd, w1 = gl[j*3+1]*dd, w2 = gl[j*3+2]*dd;
    float t2 = w0*w0 + w1*w1 + w2*w2;
    float A, Bc, Cc;
    exp_coefs(t2, A, Bc, Cc);
    (void)Cc;
    float dR[9];
    make_dR(w0, w1, w2, t2, A, Bc, dR);
    float a0 = al[j*3+0], a1 = al[j*3+1], a2 = al[j*3+2];
    float Ra0 = st[0]*a0 + st[1]*a1 + st[2]*a2;
    float Ra1 = st[3]*a0 + st[4]*a1 + st[5]*a2;
    float Ra2 = st[6]*a0 + st[7]*a1 + st[8]*a2;
    float hh = 0.5f*dd*dd;
    st[12] += st[9]*dd  + hh*Ra0;
    st[13] += st[10]*dd + hh*Ra1;
    st[14] += st[11]*dd + hh*Ra2;
    st[9] += Ra0*dd; st[10] += Ra1*dd; st[11] += Ra2*dd;
    float Rn[9];
    mm3(st, dR, Rn);
#pragma unroll
    for (int i = 0; i < 9; ++i) st[i] = Rn[i];
    st[15] += dd;
  }
}

// Hillis-Steele inclusive scan over SEG threads; buf component-major (conflict-free).
__device__ __forceinline__ void blockscan(float (*buf)[SEG], float* st, int s) {
#pragma unroll
  for (int i = 0; i < 16; ++i) buf[i][s] = st[i];
  __syncthreads();
#pragma unroll
  for (int off = 1; off < SEG; off <<= 1) {
    float pa[16];
    const bool act = (s >= off);
    if (act) {
#pragma unroll
      for (int i = 0; i < 16; ++i) pa[i] = buf[i][s - off];
    }
    __syncthreads();
    if (act) {
      compose16(pa, st, st);
#pragma unroll
      for (int i = 0; i < 16; ++i) buf[i][s] = st[i];
    }
    __syncthreads();
  }
}

// ---------------- K1: per-half-batch raw totals ----------------
__global__ __launch_bounds__(SEG, 2)
void k1_totals(const float* __restrict__ dtp, const float* __restrict__ gyp,
               const float* __restrict__ acp, float* __restrict__ ws_tot)
{
  __shared__ float buf[16][SEG];
  const int s = threadIdx.x;
  const int bid = blockIdx.x;
  const size_t base = (size_t)bid * HALF + (size_t)s * LSTEP;
  float dl[LSTEP], gl[LSTEP*3], al[LSTEP*3];
  load_seg(dtp, gyp, acp, base, dl, gl, al);
  float st[16];
  integrate_seg(dl, gl, al, st);
  blockscan(buf, st, s);
  if (s < 16) ws_tot[(size_t)bid*16 + s] = buf[s][SEG-1];
}

// ---------------- K2: scan + merged output/cov loop (pre-rotated frame) ----------------
__global__ __launch_bounds__(SEG, 2)
void k2_main(const float* __restrict__ dtp, const float* __restrict__ gyp,
             const float* __restrict__ acp, const float* __restrict__ ip0,
             const float* __restrict__ iR0, const float* __restrict__ iv0,
             float* __restrict__ out, const float* __restrict__ ws_tot,
             float* __restrict__ ws_part, int B)
{
  // smem union: scan buf [16][256] (16KB) first, then rot stage [HALF*9] (36.9KB)
  __shared__ float smem[9 * HALF];
  __shared__ float rbuf[4][48];
  float (*buf)[SEG] = reinterpret_cast<float(*)[SEG]>(smem);

  const int s = threadIdx.x;
  const int bid = blockIdx.x;
  const int b = bid >> 1, h = bid & 1;
  const size_t base = (size_t)bid * HALF + (size_t)s * LSTEP;
  const size_t NBF = (size_t)B * FCNT;
  float* orot = out;
  float* ovel = out + NBF * 9;
  float* opos = out + NBF * 12;

  {
    float dl[LSTEP], gl[LSTEP*3], al[LSTEP*3];
    load_seg(dtp, gyp, acp, base, dl, gl, al);
    float st[16];
    integrate_seg(dl, gl, al, st);
    blockscan(buf, st, s);
  }

  // init transforms (uniform broadcast loads)
  float R0g[9];
#pragma unroll
  for (int i = 0; i < 9; ++i) R0g[i] = iR0[i];
  const float p0x = ip0[0], p0y = ip0[1], p0z = ip0[2];
  const float v0x = iv0[0], v0y = iv0[1], v0z = iv0[2];

  // full-chain raw totals from ws, then prime (rotate by R0)
  float Tt, Tvp0, Tvp1, Tvp2, Tpp0, Tpp1, Tpp2;
  float t0[16];
  {
    float t1[16], TF[16];
    const float* q0 = ws_tot + (size_t)(b*2) * 16;
#pragma unroll
    for (int i = 0; i < 16; ++i) { t0[i] = q0[i]; t1[i] = q0[16+i]; }
    compose16(t0, t1, TF);
    Tt = TF[15];
    Tvp0 = R0g[0]*TF[9] + R0g[1]*TF[10] + R0g[2]*TF[11];
    Tvp1 = R0g[3]*TF[9] + R0g[4]*TF[10] + R0g[5]*TF[11];
    Tvp2 = R0g[6]*TF[9] + R0g[7]*TF[10] + R0g[8]*TF[11];
    Tpp0 = R0g[0]*TF[12] + R0g[1]*TF[13] + R0g[2]*TF[14];
    Tpp1 = R0g[3]*TF[12] + R0g[4]*TF[13] + R0g[5]*TF[14];
    Tpp2 = R0g[6]*TF[12] + R0g[7]*TF[13] + R0g[8]*TF[14];
  }

  // raw exclusive carry for my segment (full chain)
  float cr[16];
  if (s == 0) {
    cr[0]=1;cr[1]=0;cr[2]=0; cr[3]=0;cr[4]=1;cr[5]=0; cr[6]=0;cr[7]=0;cr[8]=1;
#pragma unroll
    for (int i = 9; i < 16; ++i) cr[i] = 0.f;
  } else {
#pragma unroll
    for (int i = 0; i < 16; ++i) cr[i] = buf[i][s-1];
  }
  if (h) compose16(t0, cr, cr);

  __syncthreads();   // all scan-buf reads done; smem becomes the rot stage

  // primed carry: tR = R0@cR, tv = R0@cv, tp = R0@cp
  float tR[9];
  mm3(R0g, cr, tR);
  float tv0 = R0g[0]*cr[9] + R0g[1]*cr[10] + R0g[2]*cr[11];
  float tv1 = R0g[3]*cr[9] + R0g[4]*cr[10] + R0g[5]*cr[11];
  float tv2 = R0g[6]*cr[9] + R0g[7]*cr[10] + R0g[8]*cr[11];
  float tp0 = R0g[0]*cr[12] + R0g[1]*cr[13] + R0g[2]*cr[14];
  float tp1 = R0g[3]*cr[12] + R0g[4]*cr[13] + R0g[5]*cr[14];
  float tp2 = R0g[6]*cr[12] + R0g[7]*cr[13] + R0g[8]*cr[14];
  float ctt = cr[15];

  // ---------------- merged loop: outputs + covariance sums (primed frame) ----------------
  float dl[LSTEP], gl[LSTEP*3], al[LSTEP*3];
  load_seg(dtp, gyp, acp, base, dl, gl, al);

  float aS0=0,aS1=0,aS2=0,aS3=0,aS4=0,aS5=0;
  float aU0=0,aU1=0,aU2=0,aU3=0,aU4=0,aU5=0,aU6=0,aU7=0,aU8=0;
  float aV0=0,aV1=0,aV2=0,aV3=0,aV4=0,aV5=0,aV6=0,aV7=0,aV8=0;
  float b220=0,b221=0,b222=0,b223=0,b224=0,b225=0;
  float b230=0,b231=0,b232=0,b233=0,b234=0,b235=0,b236=0,b237=0,b238=0;
  float b330=0,b331=0,b332=0,b333=0,b334=0,b335=0;
  float sa=0.f, sb=0.f, sc=0.f;
  float vloc[LSTEP*3], ploc[LSTEP*3];

#pragma unroll
  for (int j = 0; j < LSTEP; ++j) {
    const float dd = dl[j];
    const float w0 = gl[j*3+0]*dd, w1 = gl[j*3+1]*dd, w2 = gl[j*3+2]*dd;
    const float t2 = w0*w0 + w1*w1 + w2*w2;
    float A, Bc, Cc;
    exp_coefs(t2, A, Bc, Cc);
    float dR[9];
    make_dR(w0, w1, w2, t2, A, Bc, dR);
    // right Jacobian Jr = I - Bc*S(w) + Cc*(w w^T - t2 I)
    float J[9];
    {
      float w01 = w0*w1, w02 = w0*w2, w12 = w1*w2;
      J[0] = 1.f + Cc*(w0*w0 - t2); J[1] =  Bc*w2 + Cc*w01;        J[2] = -Bc*w1 + Cc*w02;
      J[3] = -Bc*w2 + Cc*w01;       J[4] = 1.f + Cc*(w1*w1 - t2);  J[5] =  Bc*w0 + Cc*w12;
      J[6] =  Bc*w1 + Cc*w02;       J[7] = -Bc*w0 + Cc*w12;        J[8] = 1.f + Cc*(w2*w2 - t2);
    }
    const float a0 = al[j*3+0], a1 = al[j*3+1], a2 = al[j*3+2];
    const float Ra0 = tR[0]*a0 + tR[1]*a1 + tR[2]*a2;
    const float Ra1 = tR[3]*a0 + tR[4]*a1 + tR[5]*a2;
    const float Ra2 = tR[6]*a0 + tR[7]*a1 + tR[8]*a2;
    const float hh = 0.5f*dd*dd;
    tp0 += tv0*dd + hh*Ra0;
    tp1 += tv1*dd + hh*Ra1;
    tp2 += tv2*dd + hh*Ra2;
    tv0 += Ra0*dd; tv1 += Ra1*dd; tv2 += Ra2*dd;
    float Rn[9];
    mm3(tR, dR, Rn);
#pragma unroll
    for (int i = 0; i < 9; ++i) {
      tR[i] = Rn[i];
      smem[(s*LSTEP + j)*9 + i] = Rn[i];    // rot output (primed == final frame)
    }
    ctt += dd;
    vloc[j*3+0] = v0x + tv0;
    vloc[j*3+1] = v0y + tv1;
    vloc[j*3+2] = v0z + tv2 - GRAV*ctt;
    ploc[j*3+0] = p0x + v0x*ctt + tp0;
    ploc[j*3+1] = p0y + v0y*ctt + tp1;
    ploc[j*3+2] = p0z + v0z*ctt + tp2 - 0.5f*GRAV*ctt*ctt;

    // ---- covariance accumulation (primed frame; un-rotated in K3) ----
    float Q[9];
    mm3(tR, J, Q);                        // Q' = R0 @ Drs[k] @ Jr
    const float sg = GYRO_COV*dd*dd;
    const float S00 = sg*(Q[0]*Q[0] + Q[1]*Q[1] + Q[2]*Q[2]);
    const float S01 = sg*(Q[0]*Q[3] + Q[1]*Q[4] + Q[2]*Q[5]);
    const float S02 = sg*(Q[0]*Q[6] + Q[1]*Q[7] + Q[2]*Q[8]);
    const float S11 = sg*(Q[3]*Q[3] + Q[4]*Q[4] + Q[5]*Q[5]);
    const float S12 = sg*(Q[3]*Q[6] + Q[4]*Q[7] + Q[5]*Q[8]);
    const float S22 = sg*(Q[6]*Q[6] + Q[7]*Q[7] + Q[8]*Q[8]);
    const float z = Tt - ctt;
    const float wv0 = Tvp0 - tv0, wv1 = Tvp1 - tv1, wv2 = Tvp2 - tv2;
    const float wp0 = Tpp0 - tp0 - z*tv0;
    const float wp1 = Tpp1 - tp1 - z*tv1;
    const float wp2 = Tpp2 - tp2 - z*tv2;
    const float U00=S01*wv2-S02*wv1, U01=S02*wv0-S00*wv2, U02=S00*wv1-S01*wv0;
    const float U10=S11*wv2-S12*wv1, U11=S12*wv0-S01*wv2, U12=S01*wv1-S11*wv0;
    const float U20=S12*wv2-S22*wv1, U21=S22*wv0-S02*wv2, U22=S02*wv1-S12*wv0;
    const float V00=S01*wp2-S02*wp1, V01=S02*wp0-S00*wp2, V02=S00*wp1-S01*wp0;
    const float V10=S11*wp2-S12*wp1, V11=S12*wp0-S01*wp2, V12=S01*wp1-S11*wp0;
    const float V20=S12*wp2-S22*wp1, V21=S22*wp0-S02*wp2, V22=S02*wp1-S12*wp0;
    aS0+=S00; aS1+=S01; aS2+=S02; aS3+=S11; aS4+=S12; aS5+=S22;
    aU0+=U00; aU1+=U01; aU2+=U02; aU3+=U10; aU4+=U11; aU5+=U12; aU6+=U20; aU7+=U21; aU8+=U22;
    aV0+=V00; aV1+=V01; aV2+=V02; aV3+=V10; aV4+=V11; aV5+=V12; aV6+=V20; aV7+=V21; aV8+=V22;
    b220 += wv1*U20 - wv2*U10;
    b221 += wv1*U21 - wv2*U11;
    b222 += wv1*U22 - wv2*U12;
    b223 += wv2*U01 - wv0*U21;
    b224 += wv2*U02 - wv0*U22;
    b225 += wv0*U12 - wv1*U02;
    b230 += wv1*V20 - wv2*V10;
    b231 += wv1*V21 - wv2*V11;
    b232 += wv1*V22 - wv2*V12;
    b233 += wv2*V00 - wv0*V20;
    b234 += wv2*V01 - wv0*V21;
    b235 += wv2*V02 - wv0*V22;
    b236 += wv0*V10 - wv1*V00;
    b237 += wv0*V11 - wv1*V01;
    b238 += wv0*V12 - wv1*V02;
    b330 += wp1*V20 - wp2*V10;
    b331 += wp1*V21 - wp2*V11;
    b332 += wp1*V22 - wp2*V12;
    b333 += wp2*V01 - wp0*V21;
    b334 += wp2*V02 - wp0*V22;
    b335 += wp0*V12 - wp1*V02;
    const float d2 = dd*dd;
    const float aa = ACC_COV*d2;
    const float bbq = 0.5f*ACC_COV*d2*dd;
    sa += aa;
    sb += aa*z + bbq;
    sc += z*(aa*z + 2.f*bbq) + 0.25f*ACC_COV*d2*d2;
  }
  __syncthreads();

  // rot flush: lane-contiguous float4, each 128B line written whole -> no RMW
  {
    const size_t rbase = (size_t)bid * (HALF*9);
#pragma unroll
    for (int k = 0; k < 9; ++k) {
      float4 vv = *reinterpret_cast<const float4*>(&smem[k*(SEG*4) + s*4]);
      reinterpret_cast<float4*>(orot + rbase + (size_t)k*(SEG*4))[s] = vv;
    }
  }
  // vel/pos bursts (48B per thread, 16B aligned)
  {
    float4* vq = reinterpret_cast<float4*>(ovel + base*3);
#pragma unroll
    for (int k = 0; k < LSTEP*3/4; ++k)
      vq[k] = make_float4(vloc[k*4+0], vloc[k*4+1], vloc[k*4+2], vloc[k*4+3]);
    float4* pq = reinterpret_cast<float4*>(opos + base*3);
#pragma unroll
    for (int k = 0; k < LSTEP*3/4; ++k)
      pq[k] = make_float4(ploc[k*4+0], ploc[k*4+1], ploc[k*4+2], ploc[k*4+3]);
  }

  // 48-accumulator block reduction -> ws_part (overlaps with store drain)
  {
    float red[48] = {aS0,aS1,aS2,aS3,aS4,aS5,
                     aU0,aU1,aU2,aU3,aU4,aU5,aU6,aU7,aU8,
                     aV0,aV1,aV2,aV3,aV4,aV5,aV6,aV7,aV8,
                     b220,b221,b222,b223,b224,b225,
                     b230,b231,b232,b233,b234,b235,b236,b237,b238,
                     b330,b331,b332,b333,b334,b335,
                     sa,sb,sc};
#pragma unroll
    for (int i = 0; i < 48; ++i) {
      float x = red[i];
      x += __shfl_down(x, 32);
      x += __shfl_down(x, 16);
      x += __shfl_down(x, 8);
      x += __shfl_down(x, 4);
      x += __shfl_down(x, 2);
      x += __shfl_down(x, 1);
      red[i] = x;
    }
    const int lane = s & 63;
    const int wid  = s >> 6;
    if (lane == 0) {
#pragma unroll
      for (int i = 0; i < 48; ++i) rbuf[wid][i] = red[i];
    }
  }
  __syncthreads();
  if (s < 48)
    ws_part[(size_t)bid*48 + s] = rbuf[0][s] + rbuf[1][s] + rbuf[2][s] + rbuf[3][s];
}

// ---------------- K3: covariance assembly (un-rotates primed sums) ----------------
__global__ void k3_cov(const float* __restrict__ ws_tot, const float* __restrict__ ws_part,
                       const float* __restrict__ iR0, float* __restrict__ out, int B)
{
  const int b = blockIdx.x;
  if (threadIdx.x != 0) return;
  float T[48];
  const float* q0 = ws_part + (size_t)(b*2) * 48;
#pragma unroll
  for (int i = 0; i < 48; ++i) T[i] = q0[i] + q0[48+i];
  float t0[16], t1[16], TF[16];
  const float* w0 = ws_tot + (size_t)(b*2) * 16;
#pragma unroll
  for (int i = 0; i < 16; ++i) { t0[i] = w0[i]; t1[i] = w0[16+i]; }
  compose16(t0, t1, TF);
  float R0g[9];
#pragma unroll
  for (int i = 0; i < 9; ++i) R0g[i] = iR0[i];
  float TR[9];
#pragma unroll
  for (int i = 0; i < 9; ++i) TR[i] = TF[i];                       // DrF (raw)
  float Rt[9] = {TR[0],TR[3],TR[6], TR[1],TR[4],TR[7], TR[2],TR[5],TR[8]};
  // primed sums -> raw via M = R0^T M' R0
  float Smp[9] = {T[0],T[1],T[2], T[1],T[3],T[4], T[2],T[4],T[5]};
  float Ump[9] = {T[6],T[7],T[8], T[9],T[10],T[11], T[12],T[13],T[14]};
  float Vmp[9] = {T[15],T[16],T[17], T[18],T[19],T[20], T[21],T[22],T[23]};
  float W22p[9]= {T[24],T[25],T[26], T[25],T[27],T[28], T[26],T[28],T[29]};
  float W23p[9]= {T[30],T[31],T[32], T[33],T[34],T[35], T[36],T[37],T[38]};
  float W33p[9]= {T[39],T[40],T[41], T[40],T[42],T[43], T[41],T[43],T[44]};
  float Sm[9], Um[9], Vm[9], W22[9], W23[9], W33[9];
  conjT(R0g, Smp, Sm);
  conjT(R0g, Ump, Um);
  conjT(R0g, Vmp, Vm);
  conjT(R0g, W22p, W22);
  conjT(R0g, W23p, W23);
  conjT(R0g, W33p, W33);
  const float ssa = T[45], ssb = T[46], ssc = T[47];
  float T1[9], C11[9], C12[9], C13[9];
  mm3(Rt, Sm, T1);
  mm3(T1, TR, C11);
  mm3(Rt, Um, C12);
  mm3(Rt, Vm, C13);
  float* co = out + (size_t)B*FCNT*15 + (size_t)b*81;
#pragma unroll
  for (int i = 0; i < 3; ++i) {
#pragma unroll
    for (int jj = 0; jj < 3; ++jj) {
      co[i*9 + jj]       = C11[i*3+jj];
      co[i*9 + 3 + jj]   = C12[i*3+jj];
      co[i*9 + 6 + jj]   = C13[i*3+jj];
      co[(3+i)*9 + jj]     = C12[jj*3+i];
      co[(3+i)*9 + 3 + jj] = -W22[i*3+jj] + (i==jj ? ssa : 0.f);
      co[(3+i)*9 + 6 + jj] = -W23[i*3+jj] + (i==jj ? ssb : 0.f);
      co[(6+i)*9 + jj]     = C13[jj*3+i];
      co[(6+i)*9 + 3 + jj] = -W23[jj*3+i] + (i==jj ? ssb : 0.f);
      co[(6+i)*9 + 6 + jj] = -W33[i*3+jj] + (i==jj ? ssc : 0.f);
    }
  }
}

extern "C" void kernel_launch(void* const* d_in, const int* in_sizes, int n_in,
                              void* d_out, int out_size, void* d_ws, size_t ws_size,
                              hipStream_t stream) {
  const float* dt   = (const float*)d_in[0];
  const float* gyro = (const float*)d_in[1];
  const float* acc  = (const float*)d_in[2];
  const float* ip   = (const float*)d_in[3];
  const float* iR   = (const float*)d_in[4];
  const float* iv   = (const float*)d_in[5];
  float* out = (float*)d_out;
  const int B  = in_sizes[0] / FCNT;     // dt is (B, F, 1)
  const int NB = 2 * B;                  // half-batch blocks
  float* ws_tot  = (float*)d_ws;                         // NB*16 floats
  float* ws_part = ws_tot + (size_t)NB * 16;             // NB*48 floats (256KB @ B=512)
  k1_totals<<<dim3(NB), dim3(SEG), 0, stream>>>(dt, gyro, acc, ws_tot);
  k2_main<<<dim3(NB), dim3(SEG), 0, stream>>>(dt, gyro, acc, ip, iR, iv, out, ws_tot, ws_part, B);
  k3_cov<<<dim3(B), dim3(64), 0, stream>>>(ws_tot, ws_part, iR, out, B);
}

// Round 6
// 51.079 us; speedup vs baseline: 1.9493x; 1.1855x over previous
//
#include <hip/hip_runtime.h>
#include <cstddef>

#define FCNT 2048
#define SEG 512
#define LSTEP 4

#define GRAV 9.81007f
#define GYRO_COV (0.00016968f * 0.00016968f)
#define ACC_COV (0.002f * 0.002f)

// Series coefficients for SO3 Exp / right Jacobian: A=sin t/t, Bc=(1-cos t)/t^2,
// Cc=(t-sin t)/t^3.  Data has t^2 <= ~7e-4 -> series fp32-exact; trig fallback
// kept for robustness (uniformly untaken branch).
__device__ __forceinline__ void exp_coefs(float t2, float& A, float& Bc, float& Cc) {
  A  = 1.f     + t2 * (-1.f/6.f   + t2 * (1.f/120.f  + t2 * (-1.f/5040.f)));
  Bc = 0.5f    + t2 * (-1.f/24.f  + t2 * (1.f/720.f  + t2 * (-1.f/40320.f)));
  Cc = 1.f/6.f + t2 * (-1.f/120.f + t2 * (1.f/5040.f + t2 * (-1.f/362880.f)));
  if (t2 > 0.004f) {
    float t = sqrtf(t2);
    float sn = __sinf(t), cs = __cosf(t);
    A  = sn / t;
    Bc = (1.f - cs) / t2;
    Cc = (t - sn) / (t2 * t);
  }
}

// dR = I + A*S(w) + Bc*(w w^T - t2 I), row-major
__device__ __forceinline__ void make_dR(float w0, float w1, float w2, float t2,
                                        float A, float Bc, float* dR) {
  float w01 = w0*w1, w02 = w0*w2, w12 = w1*w2;
  dR[0] = 1.f + Bc*(w0*w0 - t2); dR[1] = Bc*w01 - A*w2;         dR[2] = Bc*w02 + A*w1;
  dR[3] = Bc*w01 + A*w2;         dR[4] = 1.f + Bc*(w1*w1 - t2); dR[5] = Bc*w12 - A*w0;
  dR[6] = Bc*w02 - A*w1;         dR[7] = Bc*w12 + A*w0;         dR[8] = 1.f + Bc*(w2*w2 - t2);
}

__device__ __forceinline__ void mm3(const float* a, const float* b, float* c) {
#pragma unroll
  for (int i = 0; i < 3; ++i) {
    float a0 = a[i*3+0], a1 = a[i*3+1], a2 = a[i*3+2];
    c[i*3+0] = a0*b[0] + a1*b[3] + a2*b[6];
    c[i*3+1] = a0*b[1] + a1*b[4] + a2*b[7];
    c[i*3+2] = a0*b[2] + a1*b[5] + a2*b[8];
  }
}

// M = R^T @ Mp @ R  (un-rotate a matrix accumulated in the pre-rotated frame)
__device__ __forceinline__ void conjT(const float* R, const float* Mp, float* M) {
  float tmp[9];
#pragma unroll
  for (int i = 0; i < 3; ++i)
#pragma unroll
    for (int j = 0; j < 3; ++j)
      tmp[i*3+j] = R[0+i]*Mp[0+j] + R[3+i]*Mp[3+j] + R[6+i]*Mp[6+j];  // R^T @ Mp
  mm3(tmp, R, M);
}

// o = pa (earlier) then st (later); o may alias either input.
// layout: [0..8]=R row-major, [9..11]=v, [12..14]=p, [15]=t
__device__ __forceinline__ void compose16(const float* pa, const float* stv, float* o) {
  float nR[9];
  mm3(pa, stv, nR);
  float nv0 = pa[9]  + pa[0]*stv[9] + pa[1]*stv[10] + pa[2]*stv[11];
  float nv1 = pa[10] + pa[3]*stv[9] + pa[4]*stv[10] + pa[5]*stv[11];
  float nv2 = pa[11] + pa[6]*stv[9] + pa[7]*stv[10] + pa[8]*stv[11];
  float qt = stv[15];
  float np0 = pa[12] + pa[9]*qt  + pa[0]*stv[12] + pa[1]*stv[13] + pa[2]*stv[14];
  float np1 = pa[13] + pa[10]*qt + pa[3]*stv[12] + pa[4]*stv[13] + pa[5]*stv[14];
  float np2 = pa[14] + pa[11]*qt + pa[6]*stv[12] + pa[7]*stv[13] + pa[8]*stv[14];
  float nt = pa[15] + qt;
#pragma unroll
  for (int i = 0; i < 9; ++i) o[i] = nR[i];
  o[9]=nv0; o[10]=nv1; o[11]=nv2;
  o[12]=np0; o[13]=np1; o[14]=np2;
  o[15]=nt;
}

__device__ __forceinline__ void set_identity16(float* o) {
  o[0]=1;o[1]=0;o[2]=0; o[3]=0;o[4]=1;o[5]=0; o[6]=0;o[7]=0;o[8]=1;
#pragma unroll
  for (int i = 9; i < 16; ++i) o[i] = 0.f;
}

__device__ __forceinline__ void load_seg(const float* __restrict__ dtp,
                                         const float* __restrict__ gyp,
                                         const float* __restrict__ acp,
                                         size_t base, float* dl, float* gl, float* al) {
  const float4 x0 = *reinterpret_cast<const float4*>(dtp + base);     // 16B aligned
  dl[0]=x0.x; dl[1]=x0.y; dl[2]=x0.z; dl[3]=x0.w;
  const float4* qg = reinterpret_cast<const float4*>(gyp + base*3);   // 48B aligned
  const float4* qa = reinterpret_cast<const float4*>(acp + base*3);
#pragma unroll
  for (int i = 0; i < 3; ++i) {
    float4 xg = qg[i];
    gl[i*4+0]=xg.x; gl[i*4+1]=xg.y; gl[i*4+2]=xg.z; gl[i*4+3]=xg.w;
    float4 xa = qa[i];
    al[i*4+0]=xa.x; al[i*4+1]=xa.y; al[i*4+2]=xa.z; al[i*4+3]=xa.w;
  }
}

// 4-step local integration from identity.
__device__ __forceinline__ void integrate_seg(const float* dl, const float* gl,
                                              const float* al, float* st) {
  set_identity16(st);
#pragma unroll
  for (int j = 0; j < LSTEP; ++j) {
    float dd = dl[j];
    float w0 = gl[j*3+0]*dd, w1 = gl[j*3+1]*dd, w2 = gl[j*3+2]*dd;
    float t2 = w0*w0 + w1*w1 + w2*w2;
    float A, Bc, Cc;
    exp_coefs(t2, A, Bc, Cc);
    (void)Cc;
    float dR[9];
    make_dR(w0, w1, w2, t2, A, Bc, dR);
    float a0 = al[j*3+0], a1 = al[j*3+1], a2 = al[j*3+2];
    float Ra0 = st[0]*a0 + st[1]*a1 + st[2]*a2;
    float Ra1 = st[3]*a0 + st[4]*a1 + st[5]*a2;
    float Ra2 = st[6]*a0 + st[7]*a1 + st[8]*a2;
    float hh = 0.5f*dd*dd;
    st[12] += st[9]*dd  + hh*Ra0;
    st[13] += st[10]*dd + hh*Ra1;
    st[14] += st[11]*dd + hh*Ra2;
    st[9] += Ra0*dd; st[10] += Ra1*dd; st[11] += Ra2*dd;
    float Rn[9];
    mm3(st, dR, Rn);
#pragma unroll
    for (int i = 0; i < 9; ++i) st[i] = Rn[i];
    st[15] += dd;
  }
}

// ---------------- fused kernel: one block per batch ----------------
__global__ __launch_bounds__(SEG, 2)   // empirical law: VGPR cap = 256/arg2 -> 128
void imu_fused(const float* __restrict__ dtp, const float* __restrict__ gyp,
               const float* __restrict__ acp, const float* __restrict__ ip0,
               const float* __restrict__ iR0, const float* __restrict__ iv0,
               float* __restrict__ out, int B)
{
  __shared__ float rstage[FCNT*9];    // 73728 B rot stage
  __shared__ float wtot[16*8];        // component-major wave totals/prefixes
  __shared__ float rbuf[8][48];
  __shared__ float tsum[48];

  const int s = threadIdx.x;
  const int lane = s & 63;
  const int wid = s >> 6;
  const int b = blockIdx.x;
  const size_t base = (size_t)b*FCNT + (size_t)s*LSTEP;
  const size_t NBF = (size_t)B*FCNT;
  float* orot = out;
  float* ovel = out + NBF*9;
  float* opos = out + NBF*12;
  float* ocov = out + NBF*15;

  // ---- phase A: per-thread segment transform ----
  float st[16];
  {
    float dl[LSTEP], gl[LSTEP*3], al[LSTEP*3];
    load_seg(dtp, gyp, acp, base, dl, gl, al);
    integrate_seg(dl, gl, al, st);
  }

  // ---- wave-level inclusive shuffle scan (no barriers) ----
#pragma unroll
  for (int off = 1; off < 64; off <<= 1) {
    float pa[16];
#pragma unroll
    for (int i = 0; i < 16; ++i) pa[i] = __shfl_up(st[i], off);
    if (lane >= off) compose16(pa, st, st);
  }
  if (lane == 63) {
#pragma unroll
    for (int i = 0; i < 16; ++i) wtot[i*8 + wid] = st[i];
  }
  __syncthreads();
  // ---- scan the 8 wave totals (wave 0, lanes 0..7) ----
  if (s < 8) {
    float t[16];
#pragma unroll
    for (int i = 0; i < 16; ++i) t[i] = wtot[i*8 + s];
#pragma unroll
    for (int off = 1; off < 8; off <<= 1) {
      float pa[16];
#pragma unroll
      for (int i = 0; i < 16; ++i) pa[i] = __shfl_up(t[i], off);
      if (s >= off) compose16(pa, t, t);
    }
#pragma unroll
    for (int i = 0; i < 16; ++i) wtot[i*8 + s] = t[i];
  }
  __syncthreads();

  // full-chain raw totals
  float TF[16];
#pragma unroll
  for (int i = 0; i < 16; ++i) TF[i] = wtot[i*8 + 7];

  // exclusive carry = wavePrefixExcl o laneExcl
  float cr[16];
  {
    float lex[16];
#pragma unroll
    for (int i = 0; i < 16; ++i) lex[i] = __shfl_up(st[i], 1);
    if (lane == 0) set_identity16(lex);
    if (wid == 0) {
#pragma unroll
      for (int i = 0; i < 16; ++i) cr[i] = lex[i];
    } else {
      float wx[16];
#pragma unroll
      for (int i = 0; i < 16; ++i) wx[i] = wtot[i*8 + wid - 1];
      compose16(wx, lex, cr);
    }
  }

  // ---- init transforms, primed carry/totals ----
  float R0g[9];
#pragma unroll
  for (int i = 0; i < 9; ++i) R0g[i] = iR0[i];
  const float p0x = ip0[0], p0y = ip0[1], p0z = ip0[2];
  const float v0x = iv0[0], v0y = iv0[1], v0z = iv0[2];

  const float Tt = TF[15];
  const float Tvp0 = R0g[0]*TF[9] + R0g[1]*TF[10] + R0g[2]*TF[11];
  const float Tvp1 = R0g[3]*TF[9] + R0g[4]*TF[10] + R0g[5]*TF[11];
  const float Tvp2 = R0g[6]*TF[9] + R0g[7]*TF[10] + R0g[8]*TF[11];
  const float Tpp0 = R0g[0]*TF[12] + R0g[1]*TF[13] + R0g[2]*TF[14];
  const float Tpp1 = R0g[3]*TF[12] + R0g[4]*TF[13] + R0g[5]*TF[14];
  const float Tpp2 = R0g[6]*TF[12] + R0g[7]*TF[13] + R0g[8]*TF[14];

  float tR[9];
  mm3(R0g, cr, tR);
  float tv0 = R0g[0]*cr[9] + R0g[1]*cr[10] + R0g[2]*cr[11];
  float tv1 = R0g[3]*cr[9] + R0g[4]*cr[10] + R0g[5]*cr[11];
  float tv2 = R0g[6]*cr[9] + R0g[7]*cr[10] + R0g[8]*cr[11];
  float tp0 = R0g[0]*cr[12] + R0g[1]*cr[13] + R0g[2]*cr[14];
  float tp1 = R0g[3]*cr[12] + R0g[4]*cr[13] + R0g[5]*cr[14];
  float tp2 = R0g[6]*cr[12] + R0g[7]*cr[13] + R0g[8]*cr[14];
  float ctt = cr[15];

  // ---- merged loop: outputs + cheap-exact covariance sums (primed frame) ----
  // S = sg*Rn*J*J^T*Rn^T with J*J^T = I + eps*K^2 (EXACT: K^4 = -t2*K^2),
  // eps = 2Cc - Bc^2 - Cc^2*t2  ->  S = alpha*I + beta*u u^T, u = Rn*w.
  float dl[LSTEP], gl[LSTEP*3], al[LSTEP*3];
  load_seg(dtp, gyp, acp, base, dl, gl, al);

  float aS0=0,aS1=0,aS2=0,aS3=0,aS4=0,aS5=0;
  float aU0=0,aU1=0,aU2=0,aU3=0,aU4=0,aU5=0,aU6=0,aU7=0,aU8=0;
  float aV0=0,aV1=0,aV2=0,aV3=0,aV4=0,aV5=0,aV6=0,aV7=0,aV8=0;
  float b220=0,b221=0,b222=0,b223=0,b224=0,b225=0;
  float b230=0,b231=0,b232=0,b233=0,b234=0,b235=0,b236=0,b237=0,b238=0;
  float b330=0,b331=0,b332=0,b333=0,b334=0,b335=0;
  float sa=0.f, sb=0.f, sc=0.f;
  float vloc[LSTEP*3], ploc[LSTEP*3];

#pragma unroll
  for (int j = 0; j < LSTEP; ++j) {
    const float dd = dl[j];
    const float w0 = gl[j*3+0]*dd, w1 = gl[j*3+1]*dd, w2 = gl[j*3+2]*dd;
    const float t2 = w0*w0 + w1*w1 + w2*w2;
    float A, Bc, Cc;
    exp_coefs(t2, A, Bc, Cc);
    float dR[9];
    make_dR(w0, w1, w2, t2, A, Bc, dR);
    const float a0 = al[j*3+0], a1 = al[j*3+1], a2 = al[j*3+2];
    const float Ra0 = tR[0]*a0 + tR[1]*a1 + tR[2]*a2;
    const float Ra1 = tR[3]*a0 + tR[4]*a1 + tR[5]*a2;
    const float Ra2 = tR[6]*a0 + tR[7]*a1 + tR[8]*a2;
    const float hh = 0.5f*dd*dd;
    tp0 += tv0*dd + hh*Ra0;
    tp1 += tv1*dd + hh*Ra1;
    tp2 += tv2*dd + hh*Ra2;
    tv0 += Ra0*dd; tv1 += Ra1*dd; tv2 += Ra2*dd;
    float Rn[9];
    mm3(tR, dR, Rn);
#pragma unroll
    for (int i = 0; i < 9; ++i) {
      tR[i] = Rn[i];
      rstage[((size_t)s*LSTEP + j)*9 + i] = Rn[i];
    }
    ctt += dd;
    vloc[j*3+0] = v0x + tv0;
    vloc[j*3+1] = v0y + tv1;
    vloc[j*3+2] = v0z + tv2 - GRAV*ctt;
    ploc[j*3+0] = p0x + v0x*ctt + tp0;
    ploc[j*3+1] = p0y + v0y*ctt + tp1;
    ploc[j*3+2] = p0z + v0z*ctt + tp2 - 0.5f*GRAV*ctt*ctt;

    // ---- covariance accumulation (factorized, exact) ----
    const float sg  = GYRO_COV*dd*dd;
    const float eps = 2.f*Cc - Bc*Bc - Cc*Cc*t2;
    const float alpha = sg*(1.f - eps*t2);
    const float beta  = sg*eps;
    const float u0 = tR[0]*w0 + tR[1]*w1 + tR[2]*w2;
    const float u1 = tR[3]*w0 + tR[4]*w1 + tR[5]*w2;
    const float u2 = tR[6]*w0 + tR[7]*w1 + tR[8]*w2;
    const float z = Tt - ctt;
    const float wv0 = Tvp0 - tv0, wv1 = Tvp1 - tv1, wv2 = Tvp2 - tv2;
    const float wp0 = Tpp0 - tp0 - z*tv0;
    const float wp1 = Tpp1 - tp1 - z*tv1;
    const float wp2 = Tpp2 - tp2 - z*tv2;
    const float c0 = wv1*u2 - wv2*u1;   // c = wv x u
    const float c1 = wv2*u0 - wv0*u2;
    const float c2 = wv0*u1 - wv1*u0;
    const float d0 = wp1*u2 - wp2*u1;   // d = wp x u
    const float d1 = wp2*u0 - wp0*u2;
    const float d2 = wp0*u1 - wp1*u0;
    const float bu0 = beta*u0, bu1 = beta*u1, bu2 = beta*u2;
    const float bc0 = beta*c0, bc1 = beta*c1, bc2 = beta*c2;
    const float bd0 = beta*d0, bd1 = beta*d1, bd2 = beta*d2;
    const float av0 = alpha*wv0, av1 = alpha*wv1, av2 = alpha*wv2;
    const float ap0 = alpha*wp0, ap1 = alpha*wp1, ap2 = alpha*wp2;
    const float nv2_ = wv0*wv0 + wv1*wv1 + wv2*wv2;
    const float np2_ = wp0*wp0 + wp1*wp1 + wp2*wp2;
    const float dvp  = wv0*wp0 + wv1*wp1 + wv2*wp2;
    // aS += alpha*I + beta*u u^T
    aS0 += alpha + bu0*u0; aS1 += bu0*u1; aS2 += bu0*u2;
    aS3 += alpha + bu1*u1; aS4 += bu1*u2; aS5 += alpha + bu2*u2;
    // aU += alpha*skew(wv) - beta*u c^T
    aU0 += -bu0*c0;        aU1 += -av2 - bu0*c1;  aU2 +=  av1 - bu0*c2;
    aU3 +=  av2 - bu1*c0;  aU4 += -bu1*c1;        aU5 += -av0 - bu1*c2;
    aU6 += -av1 - bu2*c0;  aU7 +=  av0 - bu2*c1;  aU8 += -bu2*c2;
    // aV += alpha*skew(wp) - beta*u d^T
    aV0 += -bu0*d0;        aV1 += -ap2 - bu0*d1;  aV2 +=  ap1 - bu0*d2;
    aV3 +=  ap2 - bu1*d0;  aV4 += -bu1*d1;        aV5 += -ap0 - bu1*d2;
    aV6 += -ap1 - bu2*d0;  aV7 +=  ap0 - bu2*d1;  aV8 += -bu2*d2;
    // b22 += alpha*(wv wv^T - |wv|^2 I) - beta*c c^T   (sym {00,01,02,11,12,22})
    b220 += av0*wv0 - alpha*nv2_ - bc0*c0;
    b221 += av0*wv1 - bc0*c1;
    b222 += av0*wv2 - bc0*c2;
    b223 += av1*wv1 - alpha*nv2_ - bc1*c1;
    b224 += av1*wv2 - bc1*c2;
    b225 += av2*wv2 - alpha*nv2_ - bc2*c2;
    // b23 += alpha*(wp wv^T - (wv.wp) I) - beta*c d^T  (row-major 9)
    b230 += ap0*wv0 - alpha*dvp - bc0*d0;
    b231 += ap0*wv1 - bc0*d1;
    b232 += ap0*wv2 - bc0*d2;
    b233 += ap1*wv0 - bc1*d0;
    b234 += ap1*wv1 - alpha*dvp - bc1*d1;
    b235 += ap1*wv2 - bc1*d2;
    b236 += ap2*wv0 - bc2*d0;
    b237 += ap2*wv1 - bc2*d1;
    b238 += ap2*wv2 - alpha*dvp - bc2*d2;
    // b33 += alpha*(wp wp^T - |wp|^2 I) - beta*d d^T   (sym)
    b330 += ap0*wp0 - alpha*np2_ - bd0*d0;
    b331 += ap0*wp1 - bd0*d1;
    b332 += ap0*wp2 - bd0*d2;
    b333 += ap1*wp1 - alpha*np2_ - bd1*d1;
    b334 += ap1*wp2 - bd1*d2;
    b335 += ap2*wp2 - alpha*np2_ - bd2*d2;
    // accel scalar terms
    const float dsq = dd*dd;
    const float aa = ACC_COV*dsq;
    const float bbq = 0.5f*ACC_COV*dsq*dd;
    sa += aa;
    sb += aa*z + bbq;
    sc += z*(aa*z + 2.f*bbq) + 0.25f*ACC_COV*dsq*dsq;
  }
  __syncthreads();

  // ---- rot flush: fully coalesced float4, whole lines ----
  {
    const float4* sm4 = reinterpret_cast<const float4*>(rstage);
    float4* g4 = reinterpret_cast<float4*>(orot + (size_t)b * FCNT * 9);
#pragma unroll
    for (int k = 0; k < 9; ++k)
      g4[k*SEG + s] = sm4[k*SEG + s];
  }
  // vel/pos bursts (48B per thread, 16B aligned)
  {
    float4* vq = reinterpret_cast<float4*>(ovel + base*3);
#pragma unroll
    for (int k = 0; k < LSTEP*3/4; ++k)
      vq[k] = make_float4(vloc[k*4+0], vloc[k*4+1], vloc[k*4+2], vloc[k*4+3]);
    float4* pq = reinterpret_cast<float4*>(opos + base*3);
#pragma unroll
    for (int k = 0; k < LSTEP*3/4; ++k)
      pq[k] = make_float4(ploc[k*4+0], ploc[k*4+1], ploc[k*4+2], ploc[k*4+3]);
  }

  // ---- 48-accumulator block reduction ----
  {
    float red[48] = {aS0,aS1,aS2,aS3,aS4,aS5,
                     aU0,aU1,aU2,aU3,aU4,aU5,aU6,aU7,aU8,
                     aV0,aV1,aV2,aV3,aV4,aV5,aV6,aV7,aV8,
                     b220,b221,b222,b223,b224,b225,
                     b230,b231,b232,b233,b234,b235,b236,b237,b238,
                     b330,b331,b332,b333,b334,b335,
                     sa,sb,sc};
#pragma unroll
    for (int i = 0; i < 48; ++i) {
      float x = red[i];
      x += __shfl_down(x, 32);
      x += __shfl_down(x, 16);
      x += __shfl_down(x, 8);
      x += __shfl_down(x, 4);
      x += __shfl_down(x, 2);
      x += __shfl_down(x, 1);
      red[i] = x;
    }
    if (lane == 0) {
#pragma unroll
      for (int i = 0; i < 48; ++i) rbuf[wid][i] = red[i];
    }
  }
  __syncthreads();
  if (s < 48) {
    float acc = rbuf[0][s];
#pragma unroll
    for (int w = 1; w < 8; ++w) acc += rbuf[w][s];
    tsum[s] = acc;
  }
  __syncthreads();

  // ---- covariance assembly (thread 0; un-rotates primed sums) ----
  if (s == 0) {
    float T[48];
#pragma unroll
    for (int i = 0; i < 48; ++i) T[i] = tsum[i];
    float TR[9];
#pragma unroll
    for (int i = 0; i < 9; ++i) TR[i] = TF[i];                       // DrF (raw)
    float Rt[9] = {TR[0],TR[3],TR[6], TR[1],TR[4],TR[7], TR[2],TR[5],TR[8]};
    float Smp[9] = {T[0],T[1],T[2], T[1],T[3],T[4], T[2],T[4],T[5]};
    float Ump[9] = {T[6],T[7],T[8], T[9],T[10],T[11], T[12],T[13],T[14]};
    float Vmp[9] = {T[15],T[16],T[17], T[18],T[19],T[20], T[21],T[22],T[23]};
    float W22p[9]= {T[24],T[25],T[26], T[25],T[27],T[28], T[26],T[28],T[29]};
    float W23p[9]= {T[30],T[31],T[32], T[33],T[34],T[35], T[36],T[37],T[38]};
    float W33p[9]= {T[39],T[40],T[41], T[40],T[42],T[43], T[41],T[43],T[44]};
    float Sm[9], Um[9], Vm[9], W22[9], W23[9], W33[9];
    conjT(R0g, Smp, Sm);
    conjT(R0g, Ump, Um);
    conjT(R0g, Vmp, Vm);
    conjT(R0g, W22p, W22);
    conjT(R0g, W23p, W23);
    conjT(R0g, W33p, W33);
    const float ssa = T[45], ssb = T[46], ssc = T[47];
    float T1[9], C11[9], C12[9], C13[9];
    mm3(Rt, Sm, T1);
    mm3(T1, TR, C11);
    mm3(Rt, Um, C12);
    mm3(Rt, Vm, C13);
    float* co = ocov + (size_t)b * 81;
#pragma unroll
    for (int i = 0; i < 3; ++i) {
#pragma unroll
      for (int jj = 0; jj < 3; ++jj) {
        co[i*9 + jj]       = C11[i*3+jj];
        co[i*9 + 3 + jj]   = C12[i*3+jj];
        co[i*9 + 6 + jj]   = C13[i*3+jj];
        co[(3+i)*9 + jj]     = C12[jj*3+i];
        co[(3+i)*9 + 3 + jj] = -W22[i*3+jj] + (i==jj ? ssa : 0.f);
        co[(3+i)*9 + 6 + jj] = -W23[i*3+jj] + (i==jj ? ssb : 0.f);
        co[(6+i)*9 + jj]     = C13[jj*3+i];
        co[(6+i)*9 + 3 + jj] = -W23[jj*3+i] + (i==jj ? ssb : 0.f);
        co[(6+i)*9 + 6 + jj] = -W33[i*3+jj] + (i==jj ? ssc : 0.f);
      }
    }
  }
}

extern "C" void kernel_launch(void* const* d_in, const int* in_sizes, int n_in,
                              void* d_out, int out_size, void* d_ws, size_t ws_size,
                              hipStream_t stream) {
  const float* dt   = (const float*)d_in[0];
  const float* gyro = (const float*)d_in[1];
  const float* acc  = (const float*)d_in[2];
  const float* ip   = (const float*)d_in[3];
  const float* iR   = (const float*)d_in[4];
  const float* iv   = (const float*)d_in[5];
  float* out = (float*)d_out;
  const int B = in_sizes[0] / FCNT;   // dt is (B, F, 1)
  imu_fused<<<dim3(B), dim3(SEG), 0, stream>>>(dt, gyro, acc, ip, iR, iv, out, B);
}